// Round 1
// baseline (94.818 us; speedup 1.0000x reference)
//
#include <hip/hip_runtime.h>

// VolumetricRayMarcher: B=4, R=65536, S=128.
// One 64-lane wave per ray, 2 samples per lane.
// out[ray] = sum_s alpha_s * T_s * rgb_s, T_s = prod_{j<s} (1 - alpha_j + 1e-10)
// alpha_s = 1 - exp(-density_s * delta_s), delta_s = 1.9/127 (s<127), 1e10 (s=127).

#define NSAMP 128
#define NEAR_T 0.1f
#define FAR_T 2.0f

__global__ __launch_bounds__(256) void VolumetricRayMarcher_kernel(
    const float* __restrict__ rgb,      // [n_rays, 128, 3]
    const float* __restrict__ density,  // [n_rays, 128]
    float* __restrict__ out,            // [n_rays, 3]
    int n_rays) {
    const int lane = threadIdx.x & 63;
    const int wave = threadIdx.x >> 6;
    const int ray  = blockIdx.x * 4 + wave;
    if (ray >= n_rays) return;

    const float DELTA = (FAR_T - NEAR_T) / (float)(NSAMP - 1);  // 1.9/127

    // ---- density: 2 samples per lane, coalesced float2 (512 B / wave) ----
    const float2 dpair = ((const float2*)(density + (size_t)ray * NSAMP))[lane];

    const float delta1 = (lane == 63) ? 1e10f : DELTA;

    const float alpha0 = 1.0f - __expf(-dpair.x * DELTA);
    const float alpha1 = 1.0f - __expf(-dpair.y * delta1);
    const float f0 = 1.0f - alpha0 + 1e-10f;
    const float f1 = 1.0f - alpha1 + 1e-10f;

    // ---- exclusive cumprod across 128 samples: wave scan of per-lane products ----
    float p = f0 * f1;
    #pragma unroll
    for (int off = 1; off < 64; off <<= 1) {
        float other = __shfl_up(p, off, 64);
        if (lane >= off) p *= other;
    }
    float excl = __shfl_up(p, 1, 64);   // product of all samples before this lane's s0
    if (lane == 0) excl = 1.0f;

    const float w0 = alpha0 * excl;
    const float w1 = alpha1 * excl * f0;

    // ---- rgb: 6 floats per lane = 2 samples, 3x float2 (1536 B / wave) ----
    const float2* rgb2 = (const float2*)(rgb + (size_t)ray * NSAMP * 3);
    const float2 a = rgb2[lane * 3 + 0];
    const float2 b = rgb2[lane * 3 + 1];
    const float2 c = rgb2[lane * 3 + 2];
    // sample s0 rgb = (a.x, a.y, b.x); sample s1 rgb = (b.y, c.x, c.y)
    float cr = w0 * a.x + w1 * b.y;
    float cg = w0 * a.y + w1 * c.x;
    float cb = w0 * b.x + w1 * c.y;

    // ---- wave reduce (butterfly) ----
    #pragma unroll
    for (int off = 32; off > 0; off >>= 1) {
        cr += __shfl_xor(cr, off, 64);
        cg += __shfl_xor(cg, off, 64);
        cb += __shfl_xor(cb, off, 64);
    }

    if (lane == 0) {
        float* o = out + (size_t)ray * 3;
        o[0] = cr;
        o[1] = cg;
        o[2] = cb;
    }
}

extern "C" void kernel_launch(void* const* d_in, const int* in_sizes, int n_in,
                              void* d_out, int out_size, void* d_ws, size_t ws_size,
                              hipStream_t stream) {
    const float* rgb     = (const float*)d_in[0];   // [B,R,S,3] f32
    const float* density = (const float*)d_in[1];   // [B,R,S]   f32
    float* out = (float*)d_out;                     // [B,R,3]   f32

    const int n_rays = in_sizes[1] / NSAMP;         // B*R = 262144
    const int blocks = (n_rays + 3) / 4;            // 4 waves (rays) per 256-thread block

    hipLaunchKernelGGL(VolumetricRayMarcher_kernel, dim3(blocks), dim3(256), 0, stream,
                       rgb, density, out, n_rays);
}